// Round 1
// baseline (306.929 us; speedup 1.0000x reference)
//
#include <hip/hip_runtime.h>
#include <math.h>

// ---------------------------------------------------------------------------
// Kernel 1: updated = x + reco; relu_out = max(updated, 0); upd_out = updated
// float4-vectorized grid-stride. upd_out may be null (no workspace fallback).
// ---------------------------------------------------------------------------
__global__ __launch_bounds__(256) void add_relu_kernel(
    const float* __restrict__ x,
    const float* __restrict__ reco,
    float* __restrict__ relu_out,
    float* __restrict__ upd_out,
    int n4)
{
    int i = blockIdx.x * blockDim.x + threadIdx.x;
    int stride = gridDim.x * blockDim.x;
    const float4* x4 = (const float4*)x;
    const float4* r4 = (const float4*)reco;
    float4* ro4 = (float4*)relu_out;
    float4* uo4 = (float4*)upd_out;
    for (; i < n4; i += stride) {
        float4 a = x4[i];
        float4 b = r4[i];
        float4 u;
        u.x = a.x + b.x;
        u.y = a.y + b.y;
        u.z = a.z + b.z;
        u.w = a.w + b.w;
        if (uo4) uo4[i] = u;
        float4 r;
        r.x = fmaxf(u.x, 0.0f);
        r.y = fmaxf(u.y, 0.0f);
        r.z = fmaxf(u.z, 0.0f);
        r.w = fmaxf(u.w, 0.0f);
        ro4[i] = r;
    }
}

// ---------------------------------------------------------------------------
// Trilinear fetch of one corner with zero-outside semantics (matches the
// reference's clip+mask: masked corners contribute exactly 0).
// TWO==1: vol_b is also sampled and added (on-the-fly x+reco fallback).
// ---------------------------------------------------------------------------
template <int TWO>
__device__ __forceinline__ float fetch_corner(
    const float* __restrict__ vol_a,
    const float* __restrict__ vol_b,
    int ix, int iy, int iz,
    int nx, int ny, int nz)
{
    bool valid = (ix >= 0) & (ix < nx) & (iy >= 0) & (iy < ny) &
                 (iz >= 0) & (iz < nz);
    if (!valid) return 0.0f;
    int idx = (ix * ny + iy) * nz + iz;
    float v = vol_a[idx];
    if (TWO) v += vol_b[idx];
    return v;
}

// ---------------------------------------------------------------------------
// Kernel 2: cone-beam forward projection. One thread per detector pixel.
// sino[view][u][v] = step_len * sum_{i=0..n_steps-1} trilinear(vol, p_i)
// p_i = src + ((i+0.5)/n_steps) * (det_pt - src); vox = p/spacing + (N-1)/2
// ---------------------------------------------------------------------------
template <int TWO>
__global__ __launch_bounds__(256) void cone_project_kernel(
    const float* __restrict__ vol_a,
    const float* __restrict__ vol_b,
    const float* __restrict__ src_pos,     // [n_views,3]
    const float* __restrict__ det_center,  // [n_views,3]
    const float* __restrict__ det_u_vec,   // [n_views,3]
    const float* __restrict__ det_v_vec,   // [n_views,3]
    const float* __restrict__ du_p,
    const float* __restrict__ dv_p,
    const float* __restrict__ spacing_p,
    const int* __restrict__ det_u_p,
    const int* __restrict__ det_v_p,
    const int* __restrict__ nsteps_p,
    float* __restrict__ sino,
    int n_views, int nx, int ny, int nz)
{
    const int det_u = *det_u_p;
    const int det_v = *det_v_p;
    const int n_steps = *nsteps_p;
    const float du = *du_p;
    const float dv = *dv_p;
    const float inv_sp = 1.0f / *spacing_p;

    long total = (long)n_views * det_u * det_v;
    long idx = (long)blockIdx.x * blockDim.x + threadIdx.x;
    if (idx >= total) return;

    const int v = (int)(idx % det_v);
    const int u = (int)((idx / det_v) % det_u);
    const int view = (int)(idx / ((long)det_u * det_v));

    const float us = ((float)u - (det_u - 1) * 0.5f) * du;
    const float vs = ((float)v - (det_v - 1) * 0.5f) * dv;

    const float sx = src_pos[view * 3 + 0];
    const float sy = src_pos[view * 3 + 1];
    const float sz = src_pos[view * 3 + 2];

    // detector point
    const float dpx = det_center[view * 3 + 0] + us * det_u_vec[view * 3 + 0] + vs * det_v_vec[view * 3 + 0];
    const float dpy = det_center[view * 3 + 1] + us * det_u_vec[view * 3 + 1] + vs * det_v_vec[view * 3 + 1];
    const float dpz = det_center[view * 3 + 2] + us * det_u_vec[view * 3 + 2] + vs * det_v_vec[view * 3 + 2];

    const float dx = dpx - sx;
    const float dy = dpy - sy;
    const float dz = dpz - sz;
    const float ray_len = sqrtf(dx * dx + dy * dy + dz * dz);
    const float step_len = ray_len / (float)n_steps;

    const float cx = (nx - 1) * 0.5f;
    const float cy = (ny - 1) * 0.5f;
    const float cz = (nz - 1) * 0.5f;

    const float inv_n = 1.0f / (float)n_steps;

    float acc = 0.0f;
    for (int i = 0; i < n_steps; ++i) {
        const float s = ((float)i + 0.5f) * inv_n;
        const float px = fmaf(s, dx, sx) * inv_sp + cx;
        const float py = fmaf(s, dy, sy) * inv_sp + cy;
        const float pz = fmaf(s, dz, sz) * inv_sp + cz;

        const float x0f = floorf(px);
        const float y0f = floorf(py);
        const float z0f = floorf(pz);
        const float fx = px - x0f;
        const float fy = py - y0f;
        const float fz = pz - z0f;
        const int x0 = (int)x0f;
        const int y0 = (int)y0f;
        const int z0 = (int)z0f;

        const float gx = 1.0f - fx;
        const float gy = 1.0f - fy;
        const float gz = 1.0f - fz;

        float samp = 0.0f;
        samp = fmaf(gx * gy * gz, fetch_corner<TWO>(vol_a, vol_b, x0,     y0,     z0,     nx, ny, nz), samp);
        samp = fmaf(gx * gy * fz, fetch_corner<TWO>(vol_a, vol_b, x0,     y0,     z0 + 1, nx, ny, nz), samp);
        samp = fmaf(gx * fy * gz, fetch_corner<TWO>(vol_a, vol_b, x0,     y0 + 1, z0,     nx, ny, nz), samp);
        samp = fmaf(gx * fy * fz, fetch_corner<TWO>(vol_a, vol_b, x0,     y0 + 1, z0 + 1, nx, ny, nz), samp);
        samp = fmaf(fx * gy * gz, fetch_corner<TWO>(vol_a, vol_b, x0 + 1, y0,     z0,     nx, ny, nz), samp);
        samp = fmaf(fx * gy * fz, fetch_corner<TWO>(vol_a, vol_b, x0 + 1, y0,     z0 + 1, nx, ny, nz), samp);
        samp = fmaf(fx * fy * gz, fetch_corner<TWO>(vol_a, vol_b, x0 + 1, y0 + 1, z0,     nx, ny, nz), samp);
        samp = fmaf(fx * fy * fz, fetch_corner<TWO>(vol_a, vol_b, x0 + 1, y0 + 1, z0 + 1, nx, ny, nz), samp);
        acc += samp;
    }

    sino[idx] = acc * step_len;
}

extern "C" void kernel_launch(void* const* d_in, const int* in_sizes, int n_in,
                              void* d_out, int out_size, void* d_ws, size_t ws_size,
                              hipStream_t stream) {
    const float* x          = (const float*)d_in[0];
    const float* reco       = (const float*)d_in[1];
    const float* src_pos    = (const float*)d_in[2];
    const float* det_center = (const float*)d_in[3];
    const float* det_u_vec  = (const float*)d_in[4];
    const float* det_v_vec  = (const float*)d_in[5];
    const float* du_p       = (const float*)d_in[6];
    const float* dv_p       = (const float*)d_in[7];
    const float* spacing_p  = (const float*)d_in[8];
    const int*   det_u_p    = (const int*)d_in[9];
    const int*   det_v_p    = (const int*)d_in[10];
    const int*   nsteps_p   = (const int*)d_in[11];

    const int n_vol = in_sizes[0];          // 256^3 = 16777216
    const int n_views = in_sizes[2] / 3;    // 8

    // cube root for volume dims
    int n = 1;
    while ((long)(n + 1) * (n + 1) * (n + 1) <= (long)n_vol) ++n;
    const int nx = n, ny = n, nz = n;

    // sino size = out_size - n_vol (relu part is the volume)
    const int sino_size = out_size - n_vol;  // 8*128*128 = 131072
    float* sino     = (float*)d_out;
    float* relu_out = (float*)d_out + sino_size;

    const bool use_ws = ws_size >= (size_t)n_vol * sizeof(float);
    float* upd = (float*)d_ws;

    // --- Pass 1: elementwise add + relu (+ stage updated volume) ---
    const int n4 = n_vol / 4;
    const int ew_blocks = 2048;
    add_relu_kernel<<<ew_blocks, 256, 0, stream>>>(
        x, reco, relu_out, use_ws ? upd : nullptr, n4);

    // --- Pass 2: cone projection ---
    const long total = (long)sino_size;
    const int blocks = (int)((total + 255) / 256);
    if (use_ws) {
        cone_project_kernel<0><<<blocks, 256, 0, stream>>>(
            upd, nullptr,
            src_pos, det_center, det_u_vec, det_v_vec,
            du_p, dv_p, spacing_p, det_u_p, det_v_p, nsteps_p,
            sino, n_views, nx, ny, nz);
    } else {
        cone_project_kernel<1><<<blocks, 256, 0, stream>>>(
            x, reco,
            src_pos, det_center, det_u_vec, det_v_vec,
            du_p, dv_p, spacing_p, det_u_p, det_v_p, nsteps_p,
            sino, n_views, nx, ny, nz);
    }
}

// Round 2
// 238.093 us; speedup vs baseline: 1.2891x; 1.2891x over previous
//
#include <hip/hip_runtime.h>
#include <math.h>

// ---------------------------------------------------------------------------
// Kernel 1: updated = x + reco; relu_out = max(updated, 0); upd_out = updated
// ---------------------------------------------------------------------------
__global__ __launch_bounds__(256) void add_relu_kernel(
    const float* __restrict__ x,
    const float* __restrict__ reco,
    float* __restrict__ relu_out,
    float* __restrict__ upd_out,
    int n4)
{
    int i = blockIdx.x * blockDim.x + threadIdx.x;
    int stride = gridDim.x * blockDim.x;
    const float4* x4 = (const float4*)x;
    const float4* r4 = (const float4*)reco;
    float4* ro4 = (float4*)relu_out;
    float4* uo4 = (float4*)upd_out;
    for (; i < n4; i += stride) {
        float4 a = x4[i];
        float4 b = r4[i];
        float4 u;
        u.x = a.x + b.x;
        u.y = a.y + b.y;
        u.z = a.z + b.z;
        u.w = a.w + b.w;
        if (uo4) uo4[i] = u;
        float4 r;
        r.x = fmaxf(u.x, 0.0f);
        r.y = fmaxf(u.y, 0.0f);
        r.z = fmaxf(u.z, 0.0f);
        r.w = fmaxf(u.w, 0.0f);
        ro4[i] = r;
    }
}

// ---------------------------------------------------------------------------
// Corner fetch with zero-outside semantics (matches reference clip+mask).
// ---------------------------------------------------------------------------
template <int TWO>
__device__ __forceinline__ float fetch_corner(
    const float* __restrict__ vol_a,
    const float* __restrict__ vol_b,
    int ix, int iy, int iz,
    int nx, int ny, int nz)
{
    bool valid = (ix >= 0) & (ix < nx) & (iy >= 0) & (iy < ny) &
                 (iz >= 0) & (iz < nz);
    if (!valid) return 0.0f;
    int idx = (ix * ny + iy) * nz + iz;
    float v = vol_a[idx];
    if (TWO) v += vol_b[idx];
    return v;
}

// Clip helper: constrain s-range so that a + s*b stays in (lo, hi).
__device__ __forceinline__ void clip_axis(float a, float b, float lo, float hi,
                                          float& t_lo, float& t_hi)
{
    if (fabsf(b) > 1e-6f) {
        float t0 = (lo - a) / b;
        float t1 = (hi - a) / b;
        float tmn = fminf(t0, t1);
        float tmx = fmaxf(t0, t1);
        t_lo = fmaxf(t_lo, tmn);
        t_hi = fminf(t_hi, tmx);
    } else {
        if (a <= lo || a >= hi) { t_lo = 1.0f; t_hi = 0.0f; }
    }
}

// ---------------------------------------------------------------------------
// Kernel 2: cone projection, 64 pixels x 4 ray-segments per 256-thread block.
// Per-pixel ray clipped to the volume slab; per-corner bounds checks retained
// so clipping precision cannot affect correctness (skipped steps are exact 0).
// ---------------------------------------------------------------------------
template <int TWO>
__global__ __launch_bounds__(256) void cone_project_seg_kernel(
    const float* __restrict__ vol_a,
    const float* __restrict__ vol_b,
    const float* __restrict__ src_pos,
    const float* __restrict__ det_center,
    const float* __restrict__ det_u_vec,
    const float* __restrict__ det_v_vec,
    const float* __restrict__ du_p,
    const float* __restrict__ dv_p,
    const float* __restrict__ spacing_p,
    const int* __restrict__ det_u_p,
    const int* __restrict__ det_v_p,
    const int* __restrict__ nsteps_p,
    float* __restrict__ sino,
    int n_views, int nx, int ny, int nz)
{
    const int det_u = *det_u_p;
    const int det_v = *det_v_p;
    const int n_steps = *nsteps_p;
    const float du = *du_p;
    const float dv = *dv_p;
    const float inv_sp = 1.0f / *spacing_p;

    const long total = (long)n_views * det_u * det_v;
    const int pix = threadIdx.x & 63;
    const int seg = threadIdx.x >> 6;   // 0..3
    const long idx = (long)blockIdx.x * 64 + pix;
    const bool live = idx < total;

    // decode pixel (clamped for dead lanes; they contribute nothing)
    const long cidx = live ? idx : 0;
    const int v = (int)(cidx % det_v);
    const int u = (int)((cidx / det_v) % det_u);
    const int view = (int)(cidx / ((long)det_u * det_v));

    const float us = ((float)u - (det_u - 1) * 0.5f) * du;
    const float vs = ((float)v - (det_v - 1) * 0.5f) * dv;

    const float sx = src_pos[view * 3 + 0];
    const float sy = src_pos[view * 3 + 1];
    const float sz = src_pos[view * 3 + 2];

    const float dpx = det_center[view * 3 + 0] + us * det_u_vec[view * 3 + 0] + vs * det_v_vec[view * 3 + 0];
    const float dpy = det_center[view * 3 + 1] + us * det_u_vec[view * 3 + 1] + vs * det_v_vec[view * 3 + 1];
    const float dpz = det_center[view * 3 + 2] + us * det_u_vec[view * 3 + 2] + vs * det_v_vec[view * 3 + 2];

    const float dx = dpx - sx;
    const float dy = dpy - sy;
    const float dz = dpz - sz;
    const float ray_len = sqrtf(dx * dx + dy * dy + dz * dz);
    const float step_len = ray_len / (float)n_steps;

    const float cx = (nx - 1) * 0.5f;
    const float cy = (ny - 1) * 0.5f;
    const float cz = (nz - 1) * 0.5f;

    // --- clip ray to s in [t_lo, t_hi] where voxel coords stay in (-1, N) ---
    // px(s) = (sx + s*dx)*inv_sp + cx = ax + s*bx  (analytic; loop below uses
    // the reference-exact formulation).
    float t_lo = 0.0f, t_hi = 1.0f;
    clip_axis(sx * inv_sp + cx, dx * inv_sp, -1.0f, (float)nx, t_lo, t_hi);
    clip_axis(sy * inv_sp + cy, dy * inv_sp, -1.0f, (float)ny, t_lo, t_hi);
    clip_axis(sz * inv_sp + cz, dz * inv_sp, -1.0f, (float)nz, t_lo, t_hi);

    // s_i = (i + 0.5)/n_steps; widen by 1 step for fp safety.
    int i_min = 0, i_max = -1;
    if (t_hi > t_lo) {
        i_min = (int)floorf(t_lo * (float)n_steps - 0.5f) - 1;
        i_max = (int)ceilf(t_hi * (float)n_steps - 0.5f) + 1;
        i_min = max(i_min, 0);
        i_max = min(i_max, n_steps - 1);
    }
    if (!live) { i_min = 0; i_max = -1; }

    // distribute [i_min, i_max] across 4 segments
    const int count = i_max - i_min + 1;
    const int per = (count + 3) >> 2;
    const int is = i_min + seg * per;
    const int ie = min(is + per - 1, i_max);

    const float inv_n = 1.0f / (float)n_steps;

    float acc = 0.0f;
    for (int i = is; i <= ie; ++i) {
        const float s = ((float)i + 0.5f) * inv_n;
        const float px = fmaf(s, dx, sx) * inv_sp + cx;
        const float py = fmaf(s, dy, sy) * inv_sp + cy;
        const float pz = fmaf(s, dz, sz) * inv_sp + cz;

        const float x0f = floorf(px);
        const float y0f = floorf(py);
        const float z0f = floorf(pz);
        const float fx = px - x0f;
        const float fy = py - y0f;
        const float fz = pz - z0f;
        const int x0 = (int)x0f;
        const int y0 = (int)y0f;
        const int z0 = (int)z0f;

        const float gx = 1.0f - fx;
        const float gy = 1.0f - fy;
        const float gz = 1.0f - fz;

        float samp = 0.0f;
        samp = fmaf(gx * gy * gz, fetch_corner<TWO>(vol_a, vol_b, x0,     y0,     z0,     nx, ny, nz), samp);
        samp = fmaf(gx * gy * fz, fetch_corner<TWO>(vol_a, vol_b, x0,     y0,     z0 + 1, nx, ny, nz), samp);
        samp = fmaf(gx * fy * gz, fetch_corner<TWO>(vol_a, vol_b, x0,     y0 + 1, z0,     nx, ny, nz), samp);
        samp = fmaf(gx * fy * fz, fetch_corner<TWO>(vol_a, vol_b, x0,     y0 + 1, z0 + 1, nx, ny, nz), samp);
        samp = fmaf(fx * gy * gz, fetch_corner<TWO>(vol_a, vol_b, x0 + 1, y0,     z0,     nx, ny, nz), samp);
        samp = fmaf(fx * gy * fz, fetch_corner<TWO>(vol_a, vol_b, x0 + 1, y0,     z0 + 1, nx, ny, nz), samp);
        samp = fmaf(fx * fy * gz, fetch_corner<TWO>(vol_a, vol_b, x0 + 1, y0 + 1, z0,     nx, ny, nz), samp);
        samp = fmaf(fx * fy * fz, fetch_corner<TWO>(vol_a, vol_b, x0 + 1, y0 + 1, z0 + 1, nx, ny, nz), samp);
        acc += samp;
    }

    // --- reduce 4 segments per pixel through LDS ---
    __shared__ float red[256];
    red[threadIdx.x] = acc;
    __syncthreads();
    if (seg == 0 && live) {
        float tot = red[pix] + red[pix + 64] + red[pix + 128] + red[pix + 192];
        sino[idx] = tot * step_len;
    }
}

extern "C" void kernel_launch(void* const* d_in, const int* in_sizes, int n_in,
                              void* d_out, int out_size, void* d_ws, size_t ws_size,
                              hipStream_t stream) {
    const float* x          = (const float*)d_in[0];
    const float* reco       = (const float*)d_in[1];
    const float* src_pos    = (const float*)d_in[2];
    const float* det_center = (const float*)d_in[3];
    const float* det_u_vec  = (const float*)d_in[4];
    const float* det_v_vec  = (const float*)d_in[5];
    const float* du_p       = (const float*)d_in[6];
    const float* dv_p       = (const float*)d_in[7];
    const float* spacing_p  = (const float*)d_in[8];
    const int*   det_u_p    = (const int*)d_in[9];
    const int*   det_v_p    = (const int*)d_in[10];
    const int*   nsteps_p   = (const int*)d_in[11];

    const int n_vol = in_sizes[0];          // 256^3
    const int n_views = in_sizes[2] / 3;    // 8

    int n = 1;
    while ((long)(n + 1) * (n + 1) * (n + 1) <= (long)n_vol) ++n;
    const int nx = n, ny = n, nz = n;

    const int sino_size = out_size - n_vol;  // 8*128*128
    float* sino     = (float*)d_out;
    float* relu_out = (float*)d_out + sino_size;

    const bool use_ws = ws_size >= (size_t)n_vol * sizeof(float);
    float* upd = (float*)d_ws;

    // --- Pass 1: elementwise add + relu (+ stage updated volume) ---
    const int n4 = n_vol / 4;
    add_relu_kernel<<<2048, 256, 0, stream>>>(
        x, reco, relu_out, use_ws ? upd : nullptr, n4);

    // --- Pass 2: cone projection (64 pixels x 4 segments per block) ---
    const int blocks = (sino_size + 63) / 64;
    if (use_ws) {
        cone_project_seg_kernel<0><<<blocks, 256, 0, stream>>>(
            upd, nullptr,
            src_pos, det_center, det_u_vec, det_v_vec,
            du_p, dv_p, spacing_p, det_u_p, det_v_p, nsteps_p,
            sino, n_views, nx, ny, nz);
    } else {
        cone_project_seg_kernel<1><<<blocks, 256, 0, stream>>>(
            x, reco,
            src_pos, det_center, det_u_vec, det_v_vec,
            du_p, dv_p, spacing_p, det_u_p, det_v_p, nsteps_p,
            sino, n_views, nx, ny, nz);
    }
}